// Round 1
// baseline (3369.402 us; speedup 1.0000x reference)
//
#include <hip/hip_runtime.h>
#include <hip/hip_bf16.h>
#include <cstddef>

// Problem constants
#define NBATCH 16
#define CCH    256   // C == O == 256
#define TT     400
#define VV     27
#define TV     10800 // T*V
#define EPSV   1e-5f

using bf16 = __hip_bfloat16;

// ---------------------------------------------------------------------------
// Generic tiled f32 GEMM: out[n,o,p] = epilogue( sum_k W[o*KC+k] * X(n,k,p) + bias[o] )
// 64x64 output tile, 256 threads (16x16), 4x4 regs/thread, K-step 16.
// MODE 0: qk   — X = x[n,c,p] + pe[p+54]           (KC=256), ep: +bias only
// MODE 1: out  — X = bf16 xa[n,sc,p]                (KC=512), ep: bn1 + x-res + leaky
// MODE 2: ff   — X = y1[n,c,p]                      (KC=256), ep: bn2 + x-res + leaky
// MODE 3: conv — X = y1b[n,kk/3, p+27*((kk%3)-1)]   (KC=768), ep: bn3 + y1b-res + leaky
// ---------------------------------------------------------------------------
template<int KC, int MODE>
__global__ __launch_bounds__(256) void gemm_kernel(
    const void*  __restrict__ Xv,
    const float* __restrict__ W,
    const float* __restrict__ bias,
    const float* __restrict__ bng, const float* __restrict__ bnb,
    const float* __restrict__ bnm, const float* __restrict__ bnv,
    const float* __restrict__ res,
    const float* __restrict__ pe,
    float* __restrict__ out)
{
    constexpr int PITCH = 68; // 68*4B = 272B row pitch: 16B-aligned, bank-shifted
    __shared__ float Wt[16][PITCH]; // Wt[j][i]  (K-slice major -> contiguous o for float4)
    __shared__ float Xs[16][PITCH]; // Xs[j][pp]

    const int tid = threadIdx.x;
    const int n  = blockIdx.z;
    const int p0 = blockIdx.x * 64;
    const int o0 = blockIdx.y * 64;
    const int tx = tid & 15, ty = tid >> 4;

    const float* Xf = (const float*)Xv;
    const bf16*  Xb = (const bf16*)Xv;

    float acc[4][4] = {};

    for (int c0 = 0; c0 < KC; c0 += 16) {
        __syncthreads();
        // --- W tile: Wt[j][i] = W[(o0+i)*KC + c0+j], coalesced along j(=c)
        #pragma unroll
        for (int r = 0; r < 4; r++) {
            int i = (tid >> 4) + r * 16;
            int j = tid & 15;
            Wt[j][i] = W[(size_t)(o0 + i) * KC + c0 + j];
        }
        // --- X tile: Xs[j][pp], coalesced along pp
        #pragma unroll
        for (int r = 0; r < 4; r++) {
            int j  = (tid >> 6) * 4 + r; // 0..15
            int pp = tid & 63;
            int p  = p0 + pp;
            float val = 0.f;
            if constexpr (MODE == 0) {
                if (p < TV) val = Xf[((size_t)n * CCH + c0 + j) * TV + p] + pe[p + 54];
            } else if constexpr (MODE == 1) {
                if (p < TV) val = __bfloat162float(Xb[((size_t)n * 512 + c0 + j) * TV + p]);
            } else if constexpr (MODE == 2) {
                if (p < TV) val = Xf[((size_t)n * CCH + c0 + j) * TV + p];
            } else {
                int kk = c0 + j;
                int c  = kk / 3;
                int kt = kk - c * 3;
                int ps = p + 27 * (kt - 1); // shift whole t-rows: stays same v
                if (p < TV && ps >= 0 && ps < TV)
                    val = Xf[((size_t)n * CCH + c) * TV + ps];
            }
            Xs[j][pp] = val;
        }
        __syncthreads();
        #pragma unroll
        for (int j = 0; j < 16; j++) {
            float4 a4 = *(const float4*)&Wt[j][ty * 4];
            float4 b4 = *(const float4*)&Xs[j][tx * 4];
            float av[4] = {a4.x, a4.y, a4.z, a4.w};
            float bv[4] = {b4.x, b4.y, b4.z, b4.w};
            #pragma unroll
            for (int r = 0; r < 4; r++)
                #pragma unroll
                for (int q = 0; q < 4; q++)
                    acc[r][q] += av[r] * bv[q];
        }
    }

    // --- epilogue ---
    #pragma unroll
    for (int r = 0; r < 4; r++) {
        int o = o0 + ty * 4 + r;
        float bi = bias[o];
        float scale = 1.f, shift = 0.f;
        if constexpr (MODE != 0) {
            float g = bng[o], b = bnb[o], m = bnm[o], v = bnv[o];
            scale = g * rsqrtf(v + EPSV);
            shift = b - m * scale;
        }
        #pragma unroll
        for (int q = 0; q < 4; q++) {
            int p = p0 + tx * 4 + q;
            if (p < TV) {
                float vR = acc[r][q] + bi;
                if constexpr (MODE != 0) {
                    vR = vR * scale + shift;
                    vR += res[((size_t)n * CCH + o) * TV + p];
                    vR = vR > 0.f ? vR : 0.1f * vR;
                }
                out[((size_t)n * CCH + o) * TV + p] = vR;
            }
        }
    }
}

// ---------------------------------------------------------------------------
// attn partial: logits[n,s,u,v] += sum_{ci<64, t in chunk} q[ci,t,u]*k[ci,t,v]
// grid (25 t-chunks of 16, N*S), 256 threads; 243 active threads x 3 (u,v) pairs
// ---------------------------------------------------------------------------
__global__ __launch_bounds__(256) void attn_partial(
    const float* __restrict__ qk, float* __restrict__ logits)
{
    __shared__ float qs[64][108]; // [ci][tt*27+u], 4 t's per sub-chunk
    __shared__ float ks[64][108];
    const int tid = threadIdx.x;
    const int tch = blockIdx.x;
    const int ns  = blockIdx.y;
    const int n = ns >> 1, s = ns & 1;

    const float* qbase = qk + ((size_t)n * CCH + s * 64) * TV;
    const float* kbase = qk + ((size_t)n * CCH + 128 + s * 64) * TV;

    float acc[3] = {0.f, 0.f, 0.f};

    for (int sub = 0; sub < 4; sub++) {
        int t0 = tch * 16 + sub * 4;
        __syncthreads();
        for (int i = tid; i < 64 * 108; i += 256) {
            int ci = i / 108, r = i - ci * 108;
            qs[ci][r] = qbase[(size_t)ci * TV + t0 * 27 + r];
            ks[ci][r] = kbase[(size_t)ci * TV + t0 * 27 + r];
        }
        __syncthreads();
        if (tid < 243) {
            #pragma unroll
            for (int r = 0; r < 3; r++) {
                int pi = tid * 3 + r;
                int u = pi / 27, v = pi - u * 27;
                float a = 0.f;
                for (int ci = 0; ci < 64; ci++) {
                    #pragma unroll
                    for (int j = 0; j < 4; j++)
                        a += qs[ci][j * 27 + u] * ks[ci][j * 27 + v];
                }
                acc[r] += a;
            }
        }
    }
    if (tid < 243) {
        #pragma unroll
        for (int r = 0; r < 3; r++)
            atomicAdd(&logits[(size_t)ns * 729 + tid * 3 + r], acc[r]);
    }
}

// ---------------------------------------------------------------------------
// softmax over v: attn[n,s,u,:] = softmax(logits/(CI*T)*alpha[s] + att0[s,u,:])
// ---------------------------------------------------------------------------
__global__ __launch_bounds__(64) void attn_softmax(
    const float* __restrict__ logits, const float* __restrict__ alphas,
    const float* __restrict__ att0, float* __restrict__ attn)
{
    const int ns = blockIdx.x;
    const int s = ns & 1;
    const int u = threadIdx.x;
    if (u < 27) {
        float row[27];
        float alpha = alphas[s];
        const float inv_ct = 1.f / 25600.f; // 1/(CI*T)
        float m = -1e30f;
        for (int v = 0; v < 27; v++) {
            float val = logits[(size_t)ns * 729 + u * 27 + v] * inv_ct * alpha
                      + att0[(size_t)(s * 27 + u) * 27 + v];
            row[v] = val;
            m = fmaxf(m, val);
        }
        float sum = 0.f;
        for (int v = 0; v < 27; v++) { row[v] = __expf(row[v] - m); sum += row[v]; }
        float inv = 1.f / sum;
        for (int v = 0; v < 27; v++)
            attn[(size_t)ns * 729 + u * 27 + v] = row[v] * inv;
    }
}

// ---------------------------------------------------------------------------
// xa[n, s*256+c, t, v] = sum_u x[n,c,t,u] * attn[n,s,u,v]  (stored bf16)
// grid (7 t-chunks of 64, C, N), 256 threads
// ---------------------------------------------------------------------------
__global__ __launch_bounds__(256) void xa_kernel(
    const float* __restrict__ x, const float* __restrict__ attn,
    bf16* __restrict__ xa)
{
    __shared__ float xs[64 * 27];
    __shared__ float at[2 * 729];
    const int tid = threadIdx.x;
    const int tch = blockIdx.x, c = blockIdx.y, n = blockIdx.z;
    const int t0 = tch * 64;
    const int nt = (t0 + 64 <= TT) ? 64 : (TT - t0);
    const int ne = nt * 27;

    for (int i = tid; i < 2 * 729; i += 256) at[i] = attn[(size_t)n * 1458 + i];
    const float* xp = x + ((size_t)n * CCH + c) * TV + t0 * 27;
    for (int i = tid; i < ne; i += 256) xs[i] = xp[i];
    __syncthreads();

    for (int s = 0; s < 2; s++) {
        bf16* op = xa + ((size_t)n * 512 + s * 256 + c) * TV + t0 * 27;
        const float* a = &at[s * 729];
        for (int e = tid; e < ne; e += 256) {
            int tl = e / 27, v = e - tl * 27;
            float accv = 0.f;
            #pragma unroll
            for (int u = 0; u < 27; u++)
                accv += xs[tl * 27 + u] * a[u * 27 + v];
            op[e] = __float2bfloat16(accv);
        }
    }
}

// ---------------------------------------------------------------------------
extern "C" void kernel_launch(void* const* d_in, const int* in_sizes, int n_in,
                              void* d_out, int out_size, void* d_ws, size_t ws_size,
                              hipStream_t stream) {
    const float* x      = (const float*)d_in[0];
    const float* pe     = (const float*)d_in[1];
    const float* in_w   = (const float*)d_in[2];
    const float* in_b   = (const float*)d_in[3];
    const float* alphas = (const float*)d_in[4];
    const float* att0   = (const float*)d_in[5];
    const float* out_w  = (const float*)d_in[6];
    const float* out_b  = (const float*)d_in[7];
    const float* bn1_g  = (const float*)d_in[8];
    const float* bn1_b  = (const float*)d_in[9];
    const float* bn1_m  = (const float*)d_in[10];
    const float* bn1_v  = (const float*)d_in[11];
    const float* ff_w   = (const float*)d_in[12];
    const float* ff_b   = (const float*)d_in[13];
    const float* bn2_g  = (const float*)d_in[14];
    const float* bn2_b  = (const float*)d_in[15];
    const float* bn2_m  = (const float*)d_in[16];
    const float* bn2_v  = (const float*)d_in[17];
    const float* t_w    = (const float*)d_in[18];
    const float* t_b    = (const float*)d_in[19];
    const float* bn3_g  = (const float*)d_in[20];
    const float* bn3_b  = (const float*)d_in[21];
    const float* bn3_m  = (const float*)d_in[22];
    const float* bn3_v  = (const float*)d_in[23];

    // workspace layout (qk f32 region later reused as bf16 xa; both 176,947,200 B)
    const size_t TENS = (size_t)NBATCH * CCH * TV * 4; // 176,947,200 bytes
    float* qk     = (float*)d_ws;
    bf16*  xa     = (bf16*)d_ws;
    float* y1     = (float*)((char*)d_ws + TENS);
    float* y1b    = (float*)((char*)d_ws + 2 * TENS);
    float* logits = (float*)((char*)d_ws + 3 * TENS);
    float* attn   = logits + NBATCH * 2 * 729;

    dim3 gg((TV + 63) / 64, CCH / 64, NBATCH); // (169, 4, 16)

    // 1) qk = in_w · (x + pos) + in_b
    gemm_kernel<256, 0><<<gg, 256, 0, stream>>>(
        x, in_w, in_b, nullptr, nullptr, nullptr, nullptr, nullptr, pe, qk);

    // 2) attention logits (atomically accumulated) -> softmax
    hipMemsetAsync(logits, 0, (size_t)NBATCH * 2 * 729 * sizeof(float), stream);
    attn_partial<<<dim3(25, NBATCH * 2), 256, 0, stream>>>(qk, logits);
    attn_softmax<<<NBATCH * 2, 64, 0, stream>>>(logits, alphas, att0, attn);

    // 3) xa = x · attn  (bf16, overwrites qk region — qk consumed above)
    xa_kernel<<<dim3(7, CCH, NBATCH), 256, 0, stream>>>(x, attn, xa);

    // 4) y1 = leaky(x + bn1(out_w · xa + out_b))
    gemm_kernel<512, 1><<<gg, 256, 0, stream>>>(
        xa, out_w, out_b, bn1_g, bn1_b, bn1_m, bn1_v, x, nullptr, y1);

    // 5) y1b = leaky(x + bn2(ff_w · y1 + ff_b))
    gemm_kernel<256, 2><<<gg, 256, 0, stream>>>(
        y1, ff_w, ff_b, bn2_g, bn2_b, bn2_m, bn2_v, x, nullptr, y1b);

    // 6) out = leaky(y1b + bn3(conv3(y1b) + t_b))
    gemm_kernel<768, 3><<<gg, 256, 0, stream>>>(
        y1b, t_w, t_b, bn3_g, bn3_b, bn3_m, bn3_v, y1b, nullptr, (float*)d_out);
}

// Round 2
// 1253.577 us; speedup vs baseline: 2.6878x; 2.6878x over previous
//
#include <hip/hip_runtime.h>
#include <hip/hip_bf16.h>
#include <cstddef>

#define NBATCH 16
#define CCH    256
#define TT     400
#define VV     27
#define TV     10800
#define EPSV   1e-5f
#define P2     10854   // padded pitch for y1b8 (27 front + 27 back)

typedef __attribute__((ext_vector_type(8))) short  short8;
typedef __attribute__((ext_vector_type(4))) float  floatx4;

__device__ __forceinline__ unsigned short f2bu(float f) {
    __hip_bfloat16 h = __float2bfloat16(f);
    return *(unsigned short*)&h;
}
__device__ __forceinline__ float bu2f(unsigned short u) {
    union { float f; unsigned int i; } c; c.i = ((unsigned int)u) << 16; return c.f;
}
__device__ __forceinline__ void gl_lds16(const void* g, void* l) {
    __builtin_amdgcn_global_load_lds(
        (const __attribute__((address_space(1))) void*)g,
        (__attribute__((address_space(3))) void*)l, 16, 0, 0);
}

// ---------------------------------------------------------------------------
// MFMA GEMM: out[n,o,p] = ep( sum_k W[o,k] * X[k,p] )  — 128x128 tile, BK=32.
// X8 layout (bf16, k-packed): [k/8][p (pitch XPITCH, +XOFF)][k%8] per n.
// W8 layout (bf16, k-packed): [k/8][o (256)][k%8].
// MODE 0: qk   KC=256, ep: +bias            -> f32 plain
// MODE 1: out  KC=512, ep: bn1+res(x)+leaky -> bf16 packed (pitch 10800)
// MODE 2: ff   KC=256, ep: bn2+res(x)+leaky -> bf16 packed (pitch 10854, off 27)
// MODE 3: conv KC=768 (k=kt*256+c, shifted-p reads of y1b8),
//              ep: bn3+res(y1b8 bf16)+leaky -> f32 plain (d_out)
// ---------------------------------------------------------------------------
template<int KC, int MODE>
__global__ __launch_bounds__(256) void mfma_gemm(
    const unsigned short* __restrict__ X8,
    const unsigned short* __restrict__ W8,
    const float* __restrict__ bias,
    const float* __restrict__ bng, const float* __restrict__ bnb,
    const float* __restrict__ bnm, const float* __restrict__ bnv,
    const void* __restrict__ resv,
    float* __restrict__ outf,
    unsigned short* __restrict__ out8)
{
    constexpr int XPITCH = (MODE == 3) ? P2 : TV;
    constexpr int XOFF   = (MODE == 3) ? 27 : 0;
    constexpr int XROWS  = (MODE == 3) ? 32 : (KC / 8);
    constexpr int OPITCH = (MODE == 2) ? P2 : TV;
    constexpr int OOFF   = (MODE == 2) ? 27 : 0;

    __shared__ short Ws[4096];   // [kg 0..3][o 0..127][8]
    __shared__ short Xs[4096];   // [kg 0..3][p 0..127][8]
    __shared__ float scs[128], shs[128];

    const int tid  = threadIdx.x;
    const int wid  = tid >> 6;
    const int lane = tid & 63;
    const int quad = lane >> 4, col = lane & 15;
    const int n  = blockIdx.z;
    const int p0 = blockIdx.x * 128;
    const int o0 = blockIdx.y * 128;
    const int wo = (wid >> 1) * 64;  // wave's o offset in tile
    const int wp = (wid & 1) * 64;   // wave's p offset in tile

    const size_t nX = (size_t)n * XROWS * XPITCH;

    floatx4 acc[4][4];
    #pragma unroll
    for (int i = 0; i < 4; i++)
        #pragma unroll
        for (int j = 0; j < 4; j++)
            acc[i][j] = (floatx4){0.f, 0.f, 0.f, 0.f};

    for (int k0 = 0; k0 < KC; k0 += 32) {
        int c0 = k0, pshift = 0;
        if constexpr (MODE == 3) {
            int kt = k0 >> 8;
            c0 = k0 & 255;
            pshift = 27 * (kt - 1);
        }
        __syncthreads();
        #pragma unroll
        for (int q = 0; q < 2; q++) {
            const int ci = wid * 2 + q;         // wave-uniform chunk id 0..7
            const int kg = ci >> 1, half = ci & 1;
            const size_t woff = ((size_t)((k0 >> 3) + kg) * 256 + o0 + half * 64 + lane) * 8;
            gl_lds16(W8 + woff, Ws + ci * 512);
            const size_t xoff = (nX + (size_t)((c0 >> 3) + kg) * XPITCH
                                 + XOFF + p0 + pshift + half * 64 + lane) * 8;
            gl_lds16(X8 + xoff, Xs + ci * 512);
        }
        __syncthreads();   // compiler drains vmcnt before barrier
        short8 a[4], b[4];
        #pragma unroll
        for (int i = 0; i < 4; i++)
            a[i] = *(const short8*)&Ws[quad * 1024 + (wo + i * 16 + col) * 8];
        #pragma unroll
        for (int j = 0; j < 4; j++)
            b[j] = *(const short8*)&Xs[quad * 1024 + (wp + j * 16 + col) * 8];
        #pragma unroll
        for (int i = 0; i < 4; i++)
            #pragma unroll
            for (int j = 0; j < 4; j++)
                acc[i][j] = __builtin_amdgcn_mfma_f32_16x16x32_bf16(a[i], b[j], acc[i][j], 0, 0, 0);
    }

    // bn/bias folded to scale/shift per o
    __syncthreads();
    if (tid < 128) {
        const int o = o0 + tid;
        float sc, sh;
        if constexpr (MODE == 0) { sc = 1.f; sh = bias[o]; }
        else {
            const float g = bng[o], b2 = bnb[o], m = bnm[o], v2 = bnv[o];
            sc = g * rsqrtf(v2 + EPSV);
            sh = bias[o] * sc + b2 - m * sc;
        }
        scs[tid] = sc; shs[tid] = sh;
    }
    __syncthreads();

    const float* resf = (const float*)resv;
    const unsigned short* res8 = (const unsigned short*)resv;

    #pragma unroll
    for (int i = 0; i < 4; i++) {
        const int ol = wo + i * 16 + quad * 4;  // local o of reg 0 (ol%4==0)
        const int ob = o0 + ol;
        #pragma unroll
        for (int j = 0; j < 4; j++) {
            const int p = p0 + wp + j * 16 + col;
            if (p >= TV) continue;
            float v[4];
            #pragma unroll
            for (int r = 0; r < 4; r++)
                v[r] = acc[i][j][r] * scs[ol + r] + shs[ol + r];
            if constexpr (MODE == 0) {
                #pragma unroll
                for (int r = 0; r < 4; r++)
                    outf[((size_t)n * 256 + ob + r) * TV + p] = v[r];
            } else if constexpr (MODE == 3) {
                const size_t roff = ((size_t)n * 32 * P2 + (size_t)(ob >> 3) * P2 + 27 + p) * 8 + (ob & 7);
                union { unsigned long long u64; unsigned short us[4]; } rr;
                rr.u64 = *(const unsigned long long*)&res8[roff];
                #pragma unroll
                for (int r = 0; r < 4; r++) {
                    float t = v[r] + bu2f(rr.us[r]);
                    t = t > 0.f ? t : 0.1f * t;
                    outf[((size_t)n * 256 + ob + r) * TV + p] = t;
                }
            } else {
                union { unsigned long long u64; unsigned short us[4]; } pk;
                #pragma unroll
                for (int r = 0; r < 4; r++) {
                    float t = v[r] + resf[((size_t)n * 256 + ob + r) * TV + p];
                    t = t > 0.f ? t : 0.1f * t;
                    pk.us[r] = f2bu(t);
                }
                *(unsigned long long*)&out8[((size_t)n * 32 * OPITCH
                    + (size_t)(ob >> 3) * OPITCH + OOFF + p) * 8 + (ob & 7)] = pk.u64;
            }
        }
    }
}

// ---------------------------------------------------------------------------
// prep: xpe8[n][c/8][p][c%8] = bf16(x + pe)   (k-packed input for qk GEMM)
// ---------------------------------------------------------------------------
__global__ __launch_bounds__(256) void prep_xpe(
    const float* __restrict__ x, const float* __restrict__ pe,
    unsigned short* __restrict__ xpe8)
{
    const int p = blockIdx.x * 256 + threadIdx.x;
    const int cg = blockIdx.y, n = blockIdx.z;
    if (p >= TV) return;
    const float pev = pe[p + 54];
    const float* xp = x + ((size_t)n * 256 + cg * 8) * TV + p;
    union { unsigned short us[8]; uint4 q; } pk;
    #pragma unroll
    for (int r = 0; r < 8; r++)
        pk.us[r] = f2bu(xp[(size_t)r * TV] + pev);
    *(uint4*)&xpe8[(((size_t)n * 32 + cg) * TV + p) * 8] = pk.q;
}

// ---------------------------------------------------------------------------
// weight pack: w8[(k/8)*256 + o]*8 + k%8 = bf16(W[o,k]); conv reorders k=kt*256+c
// ---------------------------------------------------------------------------
__global__ void pack_w(const float* __restrict__ w, unsigned short* __restrict__ w8,
                       int KCc, int conv)
{
    const int idx = blockIdx.x * 256 + threadIdx.x;
    if (idx >= 256 * KCc) return;
    const int o = idx / KCc, k = idx - o * KCc;
    float v;
    if (conv) { const int c = k & 255, kt = k >> 8; v = w[((size_t)o * 256 + c) * 3 + kt]; }
    else v = w[(size_t)o * KCc + k];
    w8[((size_t)(k >> 3) * 256 + o) * 8 + (k & 7)] = f2bu(v);
}

// zero the ±27 p-pads of y1b8 (rows n*32+cg = 512)
__global__ void zero_pads(unsigned short* __restrict__ y1b8) {
    unsigned short* base = y1b8 + (size_t)blockIdx.x * P2 * 8;
    for (int i = threadIdx.x; i < 27 * 8; i += 256) {
        base[i] = 0;
        base[10827 * 8 + i] = 0;
    }
}

// ---------------------------------------------------------------------------
// attention logits / softmax (unchanged from R1 — tiny)
// ---------------------------------------------------------------------------
__global__ __launch_bounds__(256) void attn_partial(
    const float* __restrict__ qk, float* __restrict__ logits)
{
    __shared__ float qs[64][108];
    __shared__ float ks[64][108];
    const int tid = threadIdx.x;
    const int tch = blockIdx.x;
    const int ns  = blockIdx.y;
    const int n = ns >> 1, s = ns & 1;

    const float* qbase = qk + ((size_t)n * CCH + s * 64) * TV;
    const float* kbase = qk + ((size_t)n * CCH + 128 + s * 64) * TV;

    float acc[3] = {0.f, 0.f, 0.f};
    for (int sub = 0; sub < 4; sub++) {
        const int t0 = tch * 16 + sub * 4;
        __syncthreads();
        for (int i = tid; i < 64 * 108; i += 256) {
            const int ci = i / 108, r = i - ci * 108;
            qs[ci][r] = qbase[(size_t)ci * TV + t0 * 27 + r];
            ks[ci][r] = kbase[(size_t)ci * TV + t0 * 27 + r];
        }
        __syncthreads();
        if (tid < 243) {
            #pragma unroll
            for (int r = 0; r < 3; r++) {
                const int pi = tid * 3 + r;
                const int u = pi / 27, v = pi - u * 27;
                float a = 0.f;
                for (int ci = 0; ci < 64; ci++) {
                    #pragma unroll
                    for (int j = 0; j < 4; j++)
                        a += qs[ci][j * 27 + u] * ks[ci][j * 27 + v];
                }
                acc[r] += a;
            }
        }
    }
    if (tid < 243) {
        #pragma unroll
        for (int r = 0; r < 3; r++)
            atomicAdd(&logits[(size_t)ns * 729 + tid * 3 + r], acc[r]);
    }
}

__global__ __launch_bounds__(64) void attn_softmax(
    const float* __restrict__ logits, const float* __restrict__ alphas,
    const float* __restrict__ att0, float* __restrict__ attn)
{
    const int ns = blockIdx.x;
    const int s = ns & 1;
    const int u = threadIdx.x;
    if (u < 27) {
        float row[27];
        const float alpha = alphas[s];
        const float inv_ct = 1.f / 25600.f;
        float m = -1e30f;
        for (int v = 0; v < 27; v++) {
            const float val = logits[(size_t)ns * 729 + u * 27 + v] * inv_ct * alpha
                            + att0[(size_t)(s * 27 + u) * 27 + v];
            row[v] = val;
            m = fmaxf(m, val);
        }
        float sum = 0.f;
        for (int v = 0; v < 27; v++) { row[v] = __expf(row[v] - m); sum += row[v]; }
        const float inv = 1.f / sum;
        for (int v = 0; v < 27; v++)
            attn[(size_t)ns * 729 + u * 27 + v] = row[v] * inv;
    }
}

// ---------------------------------------------------------------------------
// xa8[n][(s*256+c)/8][p][(s*256+c)%8] = bf16( sum_u x[n,c,t,u] * attn[n,s,u,v] )
// block: (t-chunk of 32, cgroup of 8, n); packed 16B writes
// ---------------------------------------------------------------------------
__global__ __launch_bounds__(256) void xa_kernel(
    const float* __restrict__ x, const float* __restrict__ attn,
    unsigned short* __restrict__ xa8)
{
    __shared__ float at[2 * 729];
    __shared__ float xs[8][32 * 27];
    const int tid = threadIdx.x;
    const int tch = blockIdx.x, cg = blockIdx.y, n = blockIdx.z;
    const int t0 = tch * 32;
    const int nt = (t0 + 32 <= TT) ? 32 : (TT - t0);
    const int ne = nt * 27;

    for (int i = tid; i < 1458; i += 256) at[i] = attn[(size_t)n * 1458 + i];
    const float* xp = x + ((size_t)n * 256 + cg * 8) * TV + t0 * 27;
    for (int cc = 0; cc < 8; cc++)
        for (int i = tid; i < ne; i += 256) xs[cc][i] = xp[(size_t)cc * TV + i];
    __syncthreads();

    for (int s = 0; s < 2; s++) {
        unsigned short* op = xa8 + (((size_t)n * 64 + s * 32 + cg) * TV + t0 * 27) * 8;
        const float* a = &at[s * 729];
        for (int e = tid; e < ne; e += 256) {
            const int tl = e / 27, v = e - tl * 27;
            float acc[8] = {};
            for (int u = 0; u < 27; u++) {
                const float av = a[u * 27 + v];
                #pragma unroll
                for (int cc = 0; cc < 8; cc++) acc[cc] += xs[cc][tl * 27 + u] * av;
            }
            union { unsigned short us[8]; uint4 q; } pk;
            #pragma unroll
            for (int cc = 0; cc < 8; cc++) pk.us[cc] = f2bu(acc[cc]);
            *(uint4*)&op[(size_t)e * 8] = pk.q;
        }
    }
}

// ---------------------------------------------------------------------------
extern "C" void kernel_launch(void* const* d_in, const int* in_sizes, int n_in,
                              void* d_out, int out_size, void* d_ws, size_t ws_size,
                              hipStream_t stream) {
    const float* x      = (const float*)d_in[0];
    const float* pe     = (const float*)d_in[1];
    const float* in_w   = (const float*)d_in[2];
    const float* in_b   = (const float*)d_in[3];
    const float* alphas = (const float*)d_in[4];
    const float* att0   = (const float*)d_in[5];
    const float* out_w  = (const float*)d_in[6];
    const float* out_b  = (const float*)d_in[7];
    const float* bn1_g  = (const float*)d_in[8];
    const float* bn1_b  = (const float*)d_in[9];
    const float* bn1_m  = (const float*)d_in[10];
    const float* bn1_v  = (const float*)d_in[11];
    const float* ff_w   = (const float*)d_in[12];
    const float* ff_b   = (const float*)d_in[13];
    const float* bn2_g  = (const float*)d_in[14];
    const float* bn2_b  = (const float*)d_in[15];
    const float* bn2_m  = (const float*)d_in[16];
    const float* bn2_v  = (const float*)d_in[17];
    const float* t_w    = (const float*)d_in[18];
    const float* t_b    = (const float*)d_in[19];
    const float* bn3_g  = (const float*)d_in[20];
    const float* bn3_b  = (const float*)d_in[21];
    const float* bn3_m  = (const float*)d_in[22];
    const float* bn3_v  = (const float*)d_in[23];

    char* ws = (char*)d_ws;
    // region A: xpe8 then y1_8 (both [16][32][10800][8] bf16)
    const size_t A_BYTES = (size_t)16 * 32 * TV * 8 * 2 + 8192;        // 88.48 MB
    // region B: qk f32 [16][256][10800] then xa8 [16][64][10800][8] bf16
    const size_t B_BYTES = (size_t)16 * 256 * TV * 4 + 8192;           // 176.9 MB
    // region C: y1b8 [16][32][10854][8] bf16 (padded pitch)
    const size_t C_BYTES = (size_t)16 * 32 * P2 * 8 * 2 + 8192;        // 88.9 MB
    unsigned short* xpe8 = (unsigned short*)ws;
    unsigned short* y1_8 = (unsigned short*)ws;                        // reuses A after GEMM1
    float*          qk   = (float*)(ws + A_BYTES);
    unsigned short* xa8  = (unsigned short*)(ws + A_BYTES);            // reuses B after attn
    unsigned short* y1b8 = (unsigned short*)(ws + A_BYTES + B_BYTES);
    char* D = ws + A_BYTES + B_BYTES + C_BYTES;
    float* logits = (float*)D;                                         // 93,312 B
    float* attn   = (float*)(D + 93440);
    unsigned short* w1_8 = (unsigned short*)(D + 2 * 93440);           // 256x256
    unsigned short* w4_8 = w1_8 + (size_t)256 * 256;                   // 256x512
    unsigned short* w5_8 = w4_8 + (size_t)256 * 512;                   // 256x256
    unsigned short* w6_8 = w5_8 + (size_t)256 * 256;                   // 256x768

    // --- prep: weights, x+pe pack, y1b8 pad zeros ---
    pack_w<<<256, 256, 0, stream>>>(in_w,  w1_8, 256, 0);
    pack_w<<<512, 256, 0, stream>>>(out_w, w4_8, 512, 0);
    pack_w<<<256, 256, 0, stream>>>(ff_w,  w5_8, 256, 0);
    pack_w<<<768, 256, 0, stream>>>(t_w,   w6_8, 768, 1);
    prep_xpe<<<dim3(43, 32, 16), 256, 0, stream>>>(x, pe, xpe8);
    zero_pads<<<512, 256, 0, stream>>>(y1b8);

    dim3 gg((TV + 127) / 128, 2, NBATCH);  // (85, 2, 16)

    // 1) qk = in_w · (x+pe) + in_b  (f32 plain)
    mfma_gemm<256, 0><<<gg, 256, 0, stream>>>(
        xpe8, w1_8, in_b, nullptr, nullptr, nullptr, nullptr, nullptr, qk, nullptr);

    // 2) attention
    hipMemsetAsync(logits, 0, (size_t)NBATCH * 2 * 729 * sizeof(float), stream);
    attn_partial<<<dim3(25, NBATCH * 2), 256, 0, stream>>>(qk, logits);
    attn_softmax<<<NBATCH * 2, 64, 0, stream>>>(logits, alphas, att0, attn);

    // 3) xa (bf16 k-packed, overwrites qk region)
    xa_kernel<<<dim3(13, 32, 16), 256, 0, stream>>>(x, attn, xa8);

    // 4) y1 = leaky(x + bn1(out_w · xa))  -> bf16 packed (region A)
    mfma_gemm<512, 1><<<gg, 256, 0, stream>>>(
        xa8, w4_8, out_b, bn1_g, bn1_b, bn1_m, bn1_v, x, nullptr, y1_8);

    // 5) y1b = leaky(x + bn2(ff_w · y1)) -> bf16 packed, padded pitch (region C)
    mfma_gemm<256, 2><<<gg, 256, 0, stream>>>(
        y1_8, w5_8, ff_b, bn2_g, bn2_b, bn2_m, bn2_v, x, nullptr, y1b8);

    // 6) out = leaky(y1b + bn3(conv3(y1b))) -> f32 d_out
    mfma_gemm<768, 3><<<gg, 256, 0, stream>>>(
        y1b8, w6_8, t_b, bn3_g, bn3_b, bn3_m, bn3_v, y1b8, (float*)d_out, nullptr);
}